// Round 1
// baseline (115.806 us; speedup 1.0000x reference)
//
#include <hip/hip_runtime.h>
#include <hip/hip_bf16.h>
#include <stdint.h>

#define DIM 768
#define BM 128
#define BN 128
#define BK 32

typedef __attribute__((ext_vector_type(8))) short short8;
typedef __attribute__((ext_vector_type(4))) float f32x4;

__device__ __forceinline__ void gload_lds16(const void* g, void* l) {
  __builtin_amdgcn_global_load_lds(
      (const __attribute__((address_space(1))) void*)g,
      (__attribute__((address_space(3))) void*)l, 16, 0, 0);
}

__device__ __forceinline__ unsigned short f2bf(float f) {
  union { __hip_bfloat16 h; unsigned short u; } cv;
  cv.h = __float2bfloat16(f);
  return cv.u;
}

__device__ __forceinline__ float bf2f(unsigned short u) {
  return __uint_as_float(((unsigned)u) << 16);
}

// ---- graph preprocessing ----------------------------------------------------

__global__ void count_kernel(const int* __restrict__ col, int E, int* __restrict__ deg) {
  int i = blockIdx.x * blockDim.x + threadIdx.x;
  if (i < E) atomicAdd(&deg[col[i]], 1);
}

// single-block scan: offs = exclusive prefix of deg; cur = copy; dinv = rsqrt(deg+1)
__global__ void scan_kernel(const int* __restrict__ deg, int* __restrict__ offs,
                            int* __restrict__ cur, float* __restrict__ dinv, int n) {
  __shared__ int s[1024];
  int t = threadIdx.x;
  int carry = 0;
  int nch = (n + 1023) >> 10;
  for (int ch = 0; ch < nch; ++ch) {
    int idx = (ch << 10) + t;
    int v = (idx < n) ? deg[idx] : 0;
    int sum = v;
    s[t] = v;
    __syncthreads();
    for (int off = 1; off < 1024; off <<= 1) {
      int u = (t >= off) ? s[t - off] : 0;
      __syncthreads();
      sum += u;
      s[t] = sum;
      __syncthreads();
    }
    int tot = s[1023];
    if (idx < n) {
      int excl = carry + sum - v;
      offs[idx] = excl;
      cur[idx]  = excl;
      dinv[idx] = rsqrtf((float)(deg[idx] + 1));
    }
    carry += tot;
    __syncthreads();
  }
  if (t == 0) offs[n] = carry;
}

__global__ void fill_kernel(const int* __restrict__ row, const int* __restrict__ col,
                            int E, int* __restrict__ cur, int* __restrict__ srcs) {
  int i = blockIdx.x * blockDim.x + threadIdx.x;
  if (i < E) {
    int c = col[i];
    int p = atomicAdd(&cur[c], 1);
    srcs[p] = row[i];
  }
}

// ---- dtype conversion -------------------------------------------------------

__global__ void cvt_x_kernel(const float* __restrict__ x, unsigned short* __restrict__ xbf, int n4) {
  int i = blockIdx.x * blockDim.x + threadIdx.x;
  if (i < n4) {
    float4 v = ((const float4*)x)[i];
    ushort4 o;
    o.x = f2bf(v.x); o.y = f2bf(v.y); o.z = f2bf(v.z); o.w = f2bf(v.w);
    ((ushort4*)xbf)[i] = o;
  }
}

// W[k][n] fp32 -> Wt[n][k] bf16 (tiled transpose)
__global__ void cvt_wt_kernel(const float* __restrict__ W, unsigned short* __restrict__ wt) {
  __shared__ float tile[32][33];
  int tx = threadIdx.x, ty = threadIdx.y;
  int k = blockIdx.y * 32 + ty, n = blockIdx.x * 32 + tx;
  tile[ty][tx] = W[k * DIM + n];
  __syncthreads();
  int nn = blockIdx.x * 32 + ty, kk = blockIdx.y * 32 + tx;
  wt[nn * DIM + kk] = f2bf(tile[tx][ty]);
}

// ---- GEMM: g[m][n] = bf16( dinv[m] * sum_k x[m][k] W[k][n] ) ---------------

__global__ __launch_bounds__(256) void gemm_kernel(
    const unsigned short* __restrict__ xbf, const unsigned short* __restrict__ wt,
    const float* __restrict__ dinv, unsigned short* __restrict__ g, int M) {
  __shared__ __align__(16) unsigned short Als[BM * BK];
  __shared__ __align__(16) unsigned short Bls[BN * BK];
  const int t = threadIdx.x;
  const int lane = t & 63;
  const int w = t >> 6;
  const int wr = w >> 1, wc = w & 1;
  const int tile_m = blockIdx.y * BM;
  const int n0 = blockIdx.x * BN;

  f32x4 acc[4][4];
#pragma unroll
  for (int i = 0; i < 4; ++i)
#pragma unroll
    for (int j = 0; j < 4; ++j) acc[i][j] = (f32x4){0.f, 0.f, 0.f, 0.f};

  for (int kt = 0; kt < DIM / BK; ++kt) {
    const int k0 = kt * BK;
    __syncthreads();
    // stage A[128][32] and Bt[128][32] bf16 tiles; XOR-swizzled global source,
    // linear LDS dest (wave-uniform base + lane*16).
#pragma unroll
    for (int it = 0; it < 2; ++it) {
      int p = it * 256 + t;
      int r = p >> 2;
      int gl = (p & 3) ^ ((r >> 1) & 3);
      int grow = tile_m + r;
      if (grow > M - 1) grow = M - 1;
      gload_lds16(xbf + (size_t)grow * DIM + k0 + gl * 8,
                  (char*)Als + (it * 256 + w * 64) * 16);
      gload_lds16(wt + (size_t)(n0 + r) * DIM + k0 + gl * 8,
                  (char*)Bls + (it * 256 + w * 64) * 16);
    }
    __syncthreads();

    short8 a[4], b[4];
#pragma unroll
    for (int mi = 0; mi < 4; ++mi) {
      int r = wr * 64 + mi * 16 + (lane & 15);
      int ph = (r * 4 + (((lane >> 4)) ^ ((r >> 1) & 3))) * 16;
      a[mi] = *(const short8*)((const char*)Als + ph);
    }
#pragma unroll
    for (int ni = 0; ni < 4; ++ni) {
      int c = wc * 64 + ni * 16 + (lane & 15);
      int ph = (c * 4 + (((lane >> 4)) ^ ((c >> 1) & 3))) * 16;
      b[ni] = *(const short8*)((const char*)Bls + ph);
    }
#pragma unroll
    for (int mi = 0; mi < 4; ++mi)
#pragma unroll
      for (int ni = 0; ni < 4; ++ni)
        acc[mi][ni] = __builtin_amdgcn_mfma_f32_16x16x32_bf16(a[mi], b[ni], acc[mi][ni], 0, 0, 0);
  }

  // epilogue: C/D layout col=lane&15, row=(lane>>4)*4+reg
#pragma unroll
  for (int mi = 0; mi < 4; ++mi) {
#pragma unroll
    for (int reg = 0; reg < 4; ++reg) {
      int m = tile_m + wr * 64 + mi * 16 + (lane >> 4) * 4 + reg;
      if (m < M) {
        float dv = dinv[m];
#pragma unroll
        for (int ni = 0; ni < 4; ++ni) {
          int n = n0 + wc * 64 + ni * 16 + (lane & 15);
          g[(size_t)m * DIM + n] = f2bf(dv * acc[mi][ni][reg]);
        }
      }
    }
  }
}

// ---- aggregation: out[c] = dinv[c]*(g[c] + sum_{incoming} g[src]) + b ------

__global__ __launch_bounds__(192) void agg_kernel(
    const unsigned short* __restrict__ g, const int* __restrict__ offs,
    const int* __restrict__ srcs, const float* __restrict__ dinv,
    const float* __restrict__ b, float* __restrict__ out) {
  int c = blockIdx.x;
  int t = threadIdx.x;  // 192 threads, 4 feats each
  const ushort4* gr = (const ushort4*)(g + (size_t)c * DIM);
  ushort4 v = gr[t];
  float a0 = bf2f(v.x), a1 = bf2f(v.y), a2 = bf2f(v.z), a3 = bf2f(v.w);
  int e0 = offs[c], e1 = offs[c + 1];
  for (int e = e0; e < e1; ++e) {
    const ushort4* gs = (const ushort4*)(g + (size_t)srcs[e] * DIM);
    ushort4 u = gs[t];
    a0 += bf2f(u.x); a1 += bf2f(u.y); a2 += bf2f(u.z); a3 += bf2f(u.w);
  }
  float dv = dinv[c];
  float4 bb = ((const float4*)b)[t];
  float4 r;
  r.x = dv * a0 + bb.x;
  r.y = dv * a1 + bb.y;
  r.z = dv * a2 + bb.z;
  r.w = dv * a3 + bb.w;
  ((float4*)(out + (size_t)c * DIM))[t] = r;
}

// ---- launch -----------------------------------------------------------------

extern "C" void kernel_launch(void* const* d_in, const int* in_sizes, int n_in,
                              void* d_out, int out_size, void* d_ws, size_t ws_size,
                              hipStream_t stream) {
  const float* x = (const float*)d_in[0];
  const int* ei = (const int*)d_in[1];
  const float* W = (const float*)d_in[2];
  const float* b = (const float*)d_in[3];
  float* out = (float*)d_out;
  const int N = in_sizes[0] / DIM;
  const int E = in_sizes[1] / 2;
  const int* row = ei;
  const int* col = ei + E;

  char* ws = (char*)d_ws;
  size_t off = 0;
  auto alloc = [&](size_t bytes) {
    size_t o = off;
    off = (off + bytes + 15) & ~(size_t)15;
    return o;
  };
  int* deg   = (int*)(ws + alloc((size_t)N * 4));
  int* offs  = (int*)(ws + alloc((size_t)(N + 1) * 4));
  int* cur   = (int*)(ws + alloc((size_t)N * 4));
  int* srcs  = (int*)(ws + alloc((size_t)E * 4));
  float* dinv = (float*)(ws + alloc((size_t)N * 4));
  unsigned short* xbf = (unsigned short*)(ws + alloc((size_t)N * DIM * 2));
  unsigned short* wt  = (unsigned short*)(ws + alloc((size_t)DIM * DIM * 2));
  unsigned short* g   = (unsigned short*)(ws + alloc((size_t)N * DIM * 2));

  hipMemsetAsync(deg, 0, (size_t)N * 4, stream);
  count_kernel<<<(E + 255) / 256, 256, 0, stream>>>(col, E, deg);
  scan_kernel<<<1, 1024, 0, stream>>>(deg, offs, cur, dinv, N);
  fill_kernel<<<(E + 255) / 256, 256, 0, stream>>>(row, col, E, cur, srcs);
  cvt_x_kernel<<<((N * DIM / 4) + 255) / 256, 256, 0, stream>>>(x, xbf, N * DIM / 4);
  cvt_wt_kernel<<<dim3(DIM / 32, DIM / 32), dim3(32, 32), 0, stream>>>(W, wt);
  gemm_kernel<<<dim3(DIM / BN, (N + BM - 1) / BM), 256, 0, stream>>>(xbf, wt, dinv, g, N);
  agg_kernel<<<N, 192, 0, stream>>>(g, offs, srcs, dinv, b, out);
}

// Round 2
// 101.445 us; speedup vs baseline: 1.1416x; 1.1416x over previous
//
#include <hip/hip_runtime.h>
#include <hip/hip_bf16.h>
#include <stdint.h>

#define DIM 768
#define BM 128
#define BN 128
#define BK 32

typedef __attribute__((ext_vector_type(8))) short short8;
typedef __attribute__((ext_vector_type(4))) float f32x4;

__device__ __forceinline__ void gload_lds16(const void* g, void* l) {
  __builtin_amdgcn_global_load_lds(
      (const __attribute__((address_space(1))) void*)g,
      (__attribute__((address_space(3))) void*)l, 16, 0, 0);
}

__device__ __forceinline__ unsigned short f2bf(float f) {
  union { __hip_bfloat16 h; unsigned short u; } cv;
  cv.h = __float2bfloat16(f);
  return cv.u;
}

__device__ __forceinline__ float bf2f(unsigned short u) {
  return __uint_as_float(((unsigned)u) << 16);
}

// ---- fused prep: zero deg + W transpose->bf16 + x->bf16 --------------------
// heterogeneous block roles: [0,576) = W-transpose tiles, [576,576+3750) = x
// conversion, [576+3750, +10) = deg zeroing.

#define WT_TILES 576      // (768/32)^2
#define CVTX_BLOCKS 3750  // 10000*768/8 / 256

__global__ __launch_bounds__(256) void prep_kernel(
    const float* __restrict__ x, const float* __restrict__ W,
    unsigned short* __restrict__ xbf, unsigned short* __restrict__ wt,
    int* __restrict__ deg, int N) {
  __shared__ float tile[32][33];
  const int b = blockIdx.x;
  const int t = threadIdx.x;
  if (b < WT_TILES) {
    // transpose one 32x32 tile of W: wt[n][k] = bf16(W[k][n])
    int bx = b % (DIM / 32), by = b / (DIM / 32);
    int n0 = bx * 32, k0 = by * 32;
    int tx = t & 31, ty = t >> 5;  // ty in 0..7
#pragma unroll
    for (int i = 0; i < 4; ++i) {
      int r = ty + i * 8;
      tile[r][tx] = W[(size_t)(k0 + r) * DIM + n0 + tx];
    }
    __syncthreads();
#pragma unroll
    for (int i = 0; i < 4; ++i) {
      int r = ty + i * 8;
      wt[(size_t)(n0 + r) * DIM + k0 + tx] = f2bf(tile[tx][r]);
    }
  } else if (b < WT_TILES + CVTX_BLOCKS) {
    // convert 8 fp32 -> 8 bf16 per thread
    int i = (b - WT_TILES) * 256 + t;
    if (i < N * DIM / 8) {
      const float4* xp = ((const float4*)x) + (size_t)i * 2;
      float4 v0 = xp[0], v1 = xp[1];
      ushort4 o0, o1;
      o0.x = f2bf(v0.x); o0.y = f2bf(v0.y); o0.z = f2bf(v0.z); o0.w = f2bf(v0.w);
      o1.x = f2bf(v1.x); o1.y = f2bf(v1.y); o1.z = f2bf(v1.z); o1.w = f2bf(v1.w);
      ushort4* op = ((ushort4*)xbf) + (size_t)i * 2;
      op[0] = o0; op[1] = o1;
    }
  } else {
    int i = (b - WT_TILES - CVTX_BLOCKS) * 256 + t;
#pragma unroll
    for (int j = 0; j < 4; ++j) {
      int idx = i * 4 + j;
      if (idx < N) deg[idx] = 0;
    }
  }
}

// ---- graph preprocessing ----------------------------------------------------

__global__ void count_kernel(const int* __restrict__ col, int E, int* __restrict__ deg) {
  int i = blockIdx.x * blockDim.x + threadIdx.x;
  if (i < E) atomicAdd(&deg[col[i]], 1);
}

// single-block shuffle scan: offs = exclusive prefix of deg; cur = copy;
// dinv = rsqrt(deg+1). 1024 threads x 10 elements, 2 barriers.
__global__ __launch_bounds__(1024) void scan_kernel(
    const int* __restrict__ deg, int* __restrict__ offs,
    int* __restrict__ cur, float* __restrict__ dinv, int n) {
  const int CH = 10;
  int t = threadIdx.x;
  int base = t * CH;
  int v[CH];
  int s = 0;
#pragma unroll
  for (int j = 0; j < CH; ++j) {
    int idx = base + j;
    v[j] = (idx < n) ? deg[idx] : 0;
    s += v[j];
  }
  int lane = t & 63, wv = t >> 6;
  int incl = s;
#pragma unroll
  for (int off = 1; off < 64; off <<= 1) {
    int u = __shfl_up(incl, off, 64);
    if (lane >= off) incl += u;
  }
  __shared__ int wsum[16], wpre[16];
  if (lane == 63) wsum[wv] = incl;
  __syncthreads();
  if (t < 16) {
    int ws = wsum[t];
    int wincl = ws;
#pragma unroll
    for (int off = 1; off < 16; off <<= 1) {
      int u = __shfl_up(wincl, off, 64);
      if (t >= off) wincl += u;
    }
    wpre[t] = wincl - ws;
    if (t == 15) offs[n] = wincl;  // grand total
  }
  __syncthreads();
  int excl = wpre[wv] + (incl - s);
#pragma unroll
  for (int j = 0; j < CH; ++j) {
    int idx = base + j;
    if (idx < n) {
      offs[idx] = excl;
      cur[idx] = excl;
      dinv[idx] = rsqrtf((float)(v[j] + 1));
      excl += v[j];
    }
  }
}

__global__ void fill_kernel(const int* __restrict__ row, const int* __restrict__ col,
                            int E, int* __restrict__ cur, int* __restrict__ srcs) {
  int i = blockIdx.x * blockDim.x + threadIdx.x;
  if (i < E) {
    int c = col[i];
    int p = atomicAdd(&cur[c], 1);
    srcs[p] = row[i];
  }
}

// ---- GEMM: g[m][n] = bf16( dinv[m] * sum_k x[m][k] W[k][n] ) ---------------

__global__ __launch_bounds__(256) void gemm_kernel(
    const unsigned short* __restrict__ xbf, const unsigned short* __restrict__ wt,
    const float* __restrict__ dinv, unsigned short* __restrict__ g, int M) {
  __shared__ __align__(16) unsigned short Als[BM * BK];
  __shared__ __align__(16) unsigned short Bls[BN * BK];
  const int t = threadIdx.x;
  const int lane = t & 63;
  const int w = t >> 6;
  const int wr = w >> 1, wc = w & 1;
  const int tile_m = blockIdx.y * BM;
  const int n0 = blockIdx.x * BN;

  f32x4 acc[4][4];
#pragma unroll
  for (int i = 0; i < 4; ++i)
#pragma unroll
    for (int j = 0; j < 4; ++j) acc[i][j] = (f32x4){0.f, 0.f, 0.f, 0.f};

  for (int kt = 0; kt < DIM / BK; ++kt) {
    const int k0 = kt * BK;
    __syncthreads();
#pragma unroll
    for (int it = 0; it < 2; ++it) {
      int p = it * 256 + t;
      int r = p >> 2;
      int gl = (p & 3) ^ ((r >> 1) & 3);
      int grow = tile_m + r;
      if (grow > M - 1) grow = M - 1;
      gload_lds16(xbf + (size_t)grow * DIM + k0 + gl * 8,
                  (char*)Als + (it * 256 + w * 64) * 16);
      gload_lds16(wt + (size_t)(n0 + r) * DIM + k0 + gl * 8,
                  (char*)Bls + (it * 256 + w * 64) * 16);
    }
    __syncthreads();

    short8 a[4], b[4];
#pragma unroll
    for (int mi = 0; mi < 4; ++mi) {
      int r = wr * 64 + mi * 16 + (lane & 15);
      int ph = (r * 4 + (((lane >> 4)) ^ ((r >> 1) & 3))) * 16;
      a[mi] = *(const short8*)((const char*)Als + ph);
    }
#pragma unroll
    for (int ni = 0; ni < 4; ++ni) {
      int c = wc * 64 + ni * 16 + (lane & 15);
      int ph = (c * 4 + (((lane >> 4)) ^ ((c >> 1) & 3))) * 16;
      b[ni] = *(const short8*)((const char*)Bls + ph);
    }
#pragma unroll
    for (int mi = 0; mi < 4; ++mi)
#pragma unroll
      for (int ni = 0; ni < 4; ++ni)
        acc[mi][ni] = __builtin_amdgcn_mfma_f32_16x16x32_bf16(a[mi], b[ni], acc[mi][ni], 0, 0, 0);
  }

#pragma unroll
  for (int mi = 0; mi < 4; ++mi) {
#pragma unroll
    for (int reg = 0; reg < 4; ++reg) {
      int m = tile_m + wr * 64 + mi * 16 + (lane >> 4) * 4 + reg;
      if (m < M) {
        float dv = dinv[m];
#pragma unroll
        for (int ni = 0; ni < 4; ++ni) {
          int n = n0 + wc * 64 + ni * 16 + (lane & 15);
          g[(size_t)m * DIM + n] = f2bf(dv * acc[mi][ni][reg]);
        }
      }
    }
  }
}

// ---- aggregation: out[c] = dinv[c]*(g[c] + sum_{incoming} g[src]) + b ------

__global__ __launch_bounds__(192) void agg_kernel(
    const unsigned short* __restrict__ g, const int* __restrict__ offs,
    const int* __restrict__ srcs, const float* __restrict__ dinv,
    const float* __restrict__ b, float* __restrict__ out) {
  int c = blockIdx.x;
  int t = threadIdx.x;  // 192 threads, 4 feats each
  const ushort4* gr = (const ushort4*)(g + (size_t)c * DIM);
  ushort4 v = gr[t];
  float a0 = bf2f(v.x), a1 = bf2f(v.y), a2 = bf2f(v.z), a3 = bf2f(v.w);
  int e0 = offs[c], e1 = offs[c + 1];
  for (int e = e0; e < e1; ++e) {
    const ushort4* gs = (const ushort4*)(g + (size_t)srcs[e] * DIM);
    ushort4 u = gs[t];
    a0 += bf2f(u.x); a1 += bf2f(u.y); a2 += bf2f(u.z); a3 += bf2f(u.w);
  }
  float dv = dinv[c];
  float4 bb = ((const float4*)b)[t];
  float4 r;
  r.x = dv * a0 + bb.x;
  r.y = dv * a1 + bb.y;
  r.z = dv * a2 + bb.z;
  r.w = dv * a3 + bb.w;
  ((float4*)(out + (size_t)c * DIM))[t] = r;
}

// ---- launch -----------------------------------------------------------------

extern "C" void kernel_launch(void* const* d_in, const int* in_sizes, int n_in,
                              void* d_out, int out_size, void* d_ws, size_t ws_size,
                              hipStream_t stream) {
  const float* x = (const float*)d_in[0];
  const int* ei = (const int*)d_in[1];
  const float* W = (const float*)d_in[2];
  const float* b = (const float*)d_in[3];
  float* out = (float*)d_out;
  const int N = in_sizes[0] / DIM;
  const int E = in_sizes[1] / 2;
  const int* row = ei;
  const int* col = ei + E;

  char* ws = (char*)d_ws;
  size_t off = 0;
  auto alloc = [&](size_t bytes) {
    size_t o = off;
    off = (off + bytes + 15) & ~(size_t)15;
    return o;
  };
  int* deg   = (int*)(ws + alloc((size_t)N * 4));
  int* offs  = (int*)(ws + alloc((size_t)(N + 1) * 4));
  int* cur   = (int*)(ws + alloc((size_t)N * 4));
  int* srcs  = (int*)(ws + alloc((size_t)E * 4));
  float* dinv = (float*)(ws + alloc((size_t)N * 4));
  unsigned short* xbf = (unsigned short*)(ws + alloc((size_t)N * DIM * 2));
  unsigned short* wt  = (unsigned short*)(ws + alloc((size_t)DIM * DIM * 2));
  unsigned short* g   = (unsigned short*)(ws + alloc((size_t)N * DIM * 2));

  int deg_blocks = (N + 1023) / 1024;  // 4 ints per thread, 256 threads
  prep_kernel<<<WT_TILES + CVTX_BLOCKS + deg_blocks, 256, 0, stream>>>(x, W, xbf, wt, deg, N);
  count_kernel<<<(E + 255) / 256, 256, 0, stream>>>(col, E, deg);
  scan_kernel<<<1, 1024, 0, stream>>>(deg, offs, cur, dinv, N);
  fill_kernel<<<(E + 255) / 256, 256, 0, stream>>>(row, col, E, cur, srcs);
  gemm_kernel<<<dim3(DIM / BN, (N + BM - 1) / BM), 256, 0, stream>>>(xbf, wt, dinv, g, N);
  agg_kernel<<<N, 192, 0, stream>>>(g, offs, srcs, dinv, b, out);
}

// Round 3
// 84.329 us; speedup vs baseline: 1.3733x; 1.2030x over previous
//
#include <hip/hip_runtime.h>
#include <hip/hip_bf16.h>
#include <stdint.h>

#define DIM 768
#define BM 128
#define BN 128
#define BK 64
#define FILL_BLOCKS 64

typedef __attribute__((ext_vector_type(8))) short short8;
typedef __attribute__((ext_vector_type(4))) float f32x4;

__device__ __forceinline__ void gload_lds16(const void* g, void* l) {
  __builtin_amdgcn_global_load_lds(
      (const __attribute__((address_space(1))) void*)g,
      (__attribute__((address_space(3))) void*)l, 16, 0, 0);
}

__device__ __forceinline__ unsigned short f2bf(float f) {
  union { __hip_bfloat16 h; unsigned short u; } cv;
  cv.h = __float2bfloat16(f);
  return cv.u;
}

__device__ __forceinline__ float bf2f(unsigned short u) {
  return __uint_as_float(((unsigned)u) << 16);
}

// ---- fused prep: zero deg + W transpose->bf16 + x->bf16 --------------------

#define WT_TILES 576      // (768/32)^2
#define CVTX_BLOCKS 3750  // 10000*768/8 / 256

__global__ __launch_bounds__(256) void prep_kernel(
    const float* __restrict__ x, const float* __restrict__ W,
    unsigned short* __restrict__ xbf, unsigned short* __restrict__ wt,
    int* __restrict__ deg, int N) {
  __shared__ float tile[32][33];
  const int b = blockIdx.x;
  const int t = threadIdx.x;
  if (b < WT_TILES) {
    int bx = b % (DIM / 32), by = b / (DIM / 32);
    int n0 = bx * 32, k0 = by * 32;
    int tx = t & 31, ty = t >> 5;
#pragma unroll
    for (int i = 0; i < 4; ++i) {
      int r = ty + i * 8;
      tile[r][tx] = W[(size_t)(k0 + r) * DIM + n0 + tx];
    }
    __syncthreads();
#pragma unroll
    for (int i = 0; i < 4; ++i) {
      int r = ty + i * 8;
      wt[(size_t)(n0 + r) * DIM + k0 + tx] = f2bf(tile[tx][r]);
    }
  } else if (b < WT_TILES + CVTX_BLOCKS) {
    int i = (b - WT_TILES) * 256 + t;
    if (i < N * DIM / 8) {
      const float4* xp = ((const float4*)x) + (size_t)i * 2;
      float4 v0 = xp[0], v1 = xp[1];
      ushort4 o0, o1;
      o0.x = f2bf(v0.x); o0.y = f2bf(v0.y); o0.z = f2bf(v0.z); o0.w = f2bf(v0.w);
      o1.x = f2bf(v1.x); o1.y = f2bf(v1.y); o1.z = f2bf(v1.z); o1.w = f2bf(v1.w);
      ushort4* op = ((ushort4*)xbf) + (size_t)i * 2;
      op[0] = o0; op[1] = o1;
    }
  } else {
    int i = (b - WT_TILES - CVTX_BLOCKS) * 256 + t;
#pragma unroll
    for (int j = 0; j < 4; ++j) {
      int idx = i * 4 + j;
      if (idx < N) deg[idx] = 0;
    }
  }
}

// ---- graph preprocessing ----------------------------------------------------

__global__ void count_kernel(const int* __restrict__ col, int E, int* __restrict__ deg) {
  int i = blockIdx.x * blockDim.x + threadIdx.x;
  if (i < E) atomicAdd(&deg[col[i]], 1);
}

// single-block shuffle scan: offs = exclusive prefix of deg; cur = copy;
// dinv = rsqrt(deg+1).
__global__ __launch_bounds__(1024) void scan_kernel(
    const int* __restrict__ deg, int* __restrict__ offs,
    int* __restrict__ cur, float* __restrict__ dinv, int n) {
  const int CH = 10;
  int t = threadIdx.x;
  int base = t * CH;
  int v[CH];
  int s = 0;
#pragma unroll
  for (int j = 0; j < CH; ++j) {
    int idx = base + j;
    v[j] = (idx < n) ? deg[idx] : 0;
    s += v[j];
  }
  int lane = t & 63, wv = t >> 6;
  int incl = s;
#pragma unroll
  for (int off = 1; off < 64; off <<= 1) {
    int u = __shfl_up(incl, off, 64);
    if (lane >= off) incl += u;
  }
  __shared__ int wsum[16], wpre[16];
  if (lane == 63) wsum[wv] = incl;
  __syncthreads();
  if (t < 16) {
    int ws = wsum[t];
    int wincl = ws;
#pragma unroll
    for (int off = 1; off < 16; off <<= 1) {
      int u = __shfl_up(wincl, off, 64);
      if (t >= off) wincl += u;
    }
    wpre[t] = wincl - ws;
    if (t == 15) offs[n] = wincl;
  }
  __syncthreads();
  int excl = wpre[wv] + (incl - s);
#pragma unroll
  for (int j = 0; j < CH; ++j) {
    int idx = base + j;
    if (idx < n) {
      offs[idx] = excl;
      cur[idx] = excl;
      dinv[idx] = rsqrtf((float)(v[j] + 1));
      excl += v[j];
    }
  }
}

// ---- GEMM (+fill in extra blocks) ------------------------------------------
// g[m][n] = bf16( dinv[m] * sum_k x[m][k] W[k][n] )
// BK=64: LDS row stride 128B (8 chunks of 16B), XOR swizzle ch^(r&7); staging
// sources pre-swizzled so LDS dest stays linear (wave-uniform + lane*16).

__global__ __launch_bounds__(256) void gemm_fill_kernel(
    const unsigned short* __restrict__ xbf, const unsigned short* __restrict__ wt,
    const float* __restrict__ dinv, unsigned short* __restrict__ g, int M,
    const int* __restrict__ row, const int* __restrict__ col, int E,
    int* __restrict__ cur, int* __restrict__ srcs, int gemmBlocks) {
  __shared__ __align__(16) unsigned short Als[BM * BK];
  __shared__ __align__(16) unsigned short Bls[BN * BK];
  const int t = threadIdx.x;

  if ((int)blockIdx.x >= gemmBlocks) {
    // fill role: CSR bucket fill via cursor atomics
    int i0 = ((int)blockIdx.x - gemmBlocks) * 256 + t;
    for (int i = i0; i < E; i += FILL_BLOCKS * 256) {
      int c = col[i];
      int p = atomicAdd(&cur[c], 1);
      srcs[p] = row[i];
    }
    return;
  }

  // bijective XCD-chunk swizzle over the gemm tiles
  int fid = blockIdx.x;
  int q = gemmBlocks >> 3, r8 = gemmBlocks & 7;
  int xcd = fid & 7, ii = fid >> 3;
  int nid = (xcd < r8 ? xcd * (q + 1) : r8 * (q + 1) + (xcd - r8) * q) + ii;
  const int tile_m = (nid / (DIM / BN)) * BM;
  const int n0 = (nid % (DIM / BN)) * BN;

  const int lane = t & 63;
  const int w = t >> 6;
  const int wr = w >> 1, wc = w & 1;

  f32x4 acc[4][4];
#pragma unroll
  for (int i = 0; i < 4; ++i)
#pragma unroll
    for (int j = 0; j < 4; ++j) acc[i][j] = (f32x4){0.f, 0.f, 0.f, 0.f};

  for (int kt = 0; kt < DIM / BK; ++kt) {  // 12 K-tiles
    const int k0 = kt * BK;
    __syncthreads();
#pragma unroll
    for (int it = 0; it < 4; ++it) {
      int p = it * 256 + t;          // 0..1023
      int r = p >> 3;                // row 0..127
      int gl = (p & 7) ^ (r & 7);    // pre-swizzled source chunk
      int ga = tile_m + r;
      if (ga > M - 1) ga = M - 1;
      gload_lds16(xbf + (size_t)ga * DIM + k0 + gl * 8, (char*)Als + p * 16);
      gload_lds16(wt + (size_t)(n0 + r) * DIM + k0 + gl * 8, (char*)Bls + p * 16);
    }
    __syncthreads();

#pragma unroll
    for (int kk = 0; kk < 2; ++kk) {
      short8 a[4], b[4];
#pragma unroll
      for (int mi = 0; mi < 4; ++mi) {
        int r = wr * 64 + mi * 16 + (lane & 15);
        int ch = kk * 4 + (lane >> 4);
        a[mi] = *(const short8*)((const char*)Als + r * 128 + ((ch ^ (r & 7)) * 16));
      }
#pragma unroll
      for (int ni = 0; ni < 4; ++ni) {
        int c = wc * 64 + ni * 16 + (lane & 15);
        int ch = kk * 4 + (lane >> 4);
        b[ni] = *(const short8*)((const char*)Bls + c * 128 + ((ch ^ (c & 7)) * 16));
      }
#pragma unroll
      for (int mi = 0; mi < 4; ++mi)
#pragma unroll
        for (int ni = 0; ni < 4; ++ni)
          acc[mi][ni] = __builtin_amdgcn_mfma_f32_16x16x32_bf16(a[mi], b[ni], acc[mi][ni], 0, 0, 0);
    }
  }

  // epilogue: C/D layout col=lane&15, row=(lane>>4)*4+reg
#pragma unroll
  for (int mi = 0; mi < 4; ++mi) {
#pragma unroll
    for (int reg = 0; reg < 4; ++reg) {
      int m = tile_m + wr * 64 + mi * 16 + (lane >> 4) * 4 + reg;
      if (m < M) {
        float dv = dinv[m];
#pragma unroll
        for (int ni = 0; ni < 4; ++ni) {
          int n = n0 + wc * 64 + ni * 16 + (lane & 15);
          g[(size_t)m * DIM + n] = f2bf(dv * acc[mi][ni][reg]);
        }
      }
    }
  }
}

// ---- aggregation: out[c] = dinv[c]*(g[c] + sum_{incoming} g[src]) + b ------
// srcs chunk staged in LDS; gathers unrolled x4 so row-loads overlap.

__global__ __launch_bounds__(192) void agg_kernel(
    const unsigned short* __restrict__ g, const int* __restrict__ offs,
    const int* __restrict__ srcs, const float* __restrict__ dinv,
    const float* __restrict__ b, float* __restrict__ out) {
  __shared__ int sidx[64];
  int c = blockIdx.x;
  int t = threadIdx.x;  // 192 threads, 4 feats each
  const ushort4* gr = (const ushort4*)(g + (size_t)c * DIM);
  ushort4 v = gr[t];
  float a0 = bf2f(v.x), a1 = bf2f(v.y), a2 = bf2f(v.z), a3 = bf2f(v.w);
  int e0 = offs[c], e1 = offs[c + 1];
  for (int base = e0; base < e1; base += 64) {
    int cnt = e1 - base;
    if (cnt > 64) cnt = 64;
    __syncthreads();
    if (t < cnt) sidx[t] = srcs[base + t];
    __syncthreads();
    int j = 0;
    for (; j + 4 <= cnt; j += 4) {
      int i0 = sidx[j], i1 = sidx[j + 1], i2 = sidx[j + 2], i3 = sidx[j + 3];
      ushort4 u0 = ((const ushort4*)(g + (size_t)i0 * DIM))[t];
      ushort4 u1 = ((const ushort4*)(g + (size_t)i1 * DIM))[t];
      ushort4 u2 = ((const ushort4*)(g + (size_t)i2 * DIM))[t];
      ushort4 u3 = ((const ushort4*)(g + (size_t)i3 * DIM))[t];
      a0 += bf2f(u0.x) + bf2f(u1.x) + bf2f(u2.x) + bf2f(u3.x);
      a1 += bf2f(u0.y) + bf2f(u1.y) + bf2f(u2.y) + bf2f(u3.y);
      a2 += bf2f(u0.z) + bf2f(u1.z) + bf2f(u2.z) + bf2f(u3.z);
      a3 += bf2f(u0.w) + bf2f(u1.w) + bf2f(u2.w) + bf2f(u3.w);
    }
    for (; j < cnt; ++j) {
      ushort4 u = ((const ushort4*)(g + (size_t)sidx[j] * DIM))[t];
      a0 += bf2f(u.x); a1 += bf2f(u.y); a2 += bf2f(u.z); a3 += bf2f(u.w);
    }
  }
  float dv = dinv[c];
  float4 bb = ((const float4*)b)[t];
  float4 r;
  r.x = dv * a0 + bb.x;
  r.y = dv * a1 + bb.y;
  r.z = dv * a2 + bb.z;
  r.w = dv * a3 + bb.w;
  ((float4*)(out + (size_t)c * DIM))[t] = r;
}

// ---- launch -----------------------------------------------------------------

extern "C" void kernel_launch(void* const* d_in, const int* in_sizes, int n_in,
                              void* d_out, int out_size, void* d_ws, size_t ws_size,
                              hipStream_t stream) {
  const float* x = (const float*)d_in[0];
  const int* ei = (const int*)d_in[1];
  const float* W = (const float*)d_in[2];
  const float* b = (const float*)d_in[3];
  float* out = (float*)d_out;
  const int N = in_sizes[0] / DIM;
  const int E = in_sizes[1] / 2;
  const int* row = ei;
  const int* col = ei + E;

  char* ws = (char*)d_ws;
  size_t off = 0;
  auto alloc = [&](size_t bytes) {
    size_t o = off;
    off = (off + bytes + 15) & ~(size_t)15;
    return o;
  };
  int* deg   = (int*)(ws + alloc((size_t)N * 4));
  int* offs  = (int*)(ws + alloc((size_t)(N + 1) * 4));
  int* cur   = (int*)(ws + alloc((size_t)N * 4));
  int* srcs  = (int*)(ws + alloc((size_t)E * 4));
  float* dinv = (float*)(ws + alloc((size_t)N * 4));
  unsigned short* xbf = (unsigned short*)(ws + alloc((size_t)N * DIM * 2));
  unsigned short* wt  = (unsigned short*)(ws + alloc((size_t)DIM * DIM * 2));
  unsigned short* g   = (unsigned short*)(ws + alloc((size_t)N * DIM * 2));

  int deg_blocks = (N + 1023) / 1024;
  int gemm_blocks = ((N + BM - 1) / BM) * (DIM / BN);

  prep_kernel<<<WT_TILES + CVTX_BLOCKS + deg_blocks, 256, 0, stream>>>(x, W, xbf, wt, deg, N);
  count_kernel<<<(E + 255) / 256, 256, 0, stream>>>(col, E, deg);
  scan_kernel<<<1, 1024, 0, stream>>>(deg, offs, cur, dinv, N);
  gemm_fill_kernel<<<gemm_blocks + FILL_BLOCKS, 256, 0, stream>>>(
      xbf, wt, dinv, g, N, row, col, E, cur, srcs, gemm_blocks);
  agg_kernel<<<N, 192, 0, stream>>>(g, offs, srcs, dinv, b, out);
}